// Round 8
// baseline (86.921 us; speedup 1.0000x reference)
//
#include <hip/hip_runtime.h>
#include <math.h>

// SGConv, single fused kernel. out[b,t,o] = bias[o] + sum_{dt,f} x[b,t+dt,f]*M[t][dt][f][o].
// sigma = ||lap||_2 reduced via tensor structure to max over endpoint mu=-+2cos(pi/129)
// of lam_max(G_mu^T G_mu) (16x16): 8 trace-normalized squarings (H^256) + Rayleigh,
// barrier-parallel (R4-proven; R6 showed single-wave wave-sync is 2x slower).
// M-structure: uat() differs from interior only at t in {0,127} => D_0 == D_127 == Dbnd,
// and M[t] is IDENTICAL for all t in [3,124] — only 7 distinct patterns. Each conv
// block builds <=4 M variants in LDS with one (fo,o) pair per thread (R5 lesson:
// never per-thread-all-fo, never stride-256 reads across tl).
// x chunk 0 prefetched to registers at entry — HBM latency hides behind sigma.

#define MU_MIN (-1.99940694f)   // -2*cos(pi/129)
#define MSTRIDE 1300            // variant stride: 1300 mod 32 = 20 -> conflict-free-ish

__device__ __forceinline__ float dot16(float x) {  // sum over a 16-lane group
  x += __shfl_xor(x, 1);
  x += __shfl_xor(x, 2);
  x += __shfl_xor(x, 4);
  x += __shfl_xor(x, 8);
  return x;
}

__global__ __launch_bounds__(256) void k_all(const float* __restrict__ adj,
                                             const float* __restrict__ W,
                                             const float* __restrict__ x,
                                             const float* __restrict__ bias,
                                             float* __restrict__ out) {
  const int bg = blockIdx.x;           // 0..63 -> 16 batches each
  const int tg = blockIdx.y;           // 0..7  -> 16 t each
  const int t0 = tg * 16, b0 = bg * 16;
  const int tid = threadIdx.x;

  __shared__ float Bsh[256], Wsh[768];
  __shared__ float dis_i[16], dis_b[16], csh[1];
  __shared__ float H0[512], Pb[512], Qb[512];
  __shared__ float scl[2], lamsh[2];
  __shared__ int jst[2];
  __shared__ float Dint[256], Dbnd[256], DDint[256], DDbnd[256];
  __shared__ float Msh[4 * MSTRIDE];
  __shared__ float xs[1600];           // 4 batches x 20 rows x (16+4 pad)

  // ---- prefetch x chunk 0 into registers (consumed after M-build) ----
  float4 xpre0, xpre1;
  {
    const int idx = tid;               // 320 float4 total
    const int cb = idx / 80, rem = idx % 80;
    const int rrow = rem >> 2, qq = rem & 3;
    int gr = t0 - 2 + rrow;
    gr = gr < 0 ? 0 : (gr > 127 ? 127 : gr);
    xpre0 = *(const float4*)(x + ((size_t)(b0 + cb) * 128 + gr) * 16 + qq * 4);
  }
  if (tid < 64) {
    const int idx = tid + 256;
    const int cb = idx / 80, rem = idx % 80;
    const int rrow = rem >> 2, qq = rem & 3;
    int gr = t0 - 2 + rrow;
    gr = gr < 0 ? 0 : (gr > 127 ? 127 : gr);
    xpre1 = *(const float4*)(x + ((size_t)(b0 + cb) * 128 + gr) * 16 + qq * 4);
  }

  // ---- B, W, degrees ----
  {
    const int f = tid >> 4, g = tid & 15;
    const float a = adj[tid];
    const float s = 1.f / (1.f + expf(-a));
    Bsh[tid] = (f == g) ? 1.f : s;     // B = feat + self-loop (asymmetric)
    Wsh[tid] = W[tid];
    Wsh[tid + 256] = W[tid + 256];
    Wsh[tid + 512] = W[tid + 512];
  }
  __syncthreads();
  if (tid < 16) {
    float rs = 0.f;
    #pragma unroll
    for (int j = 0; j < 16; j++) rs += Bsh[tid * 16 + j];  // row sums (d = sum axis=1)
    dis_i[tid] = rsqrtf(rs + 2.f);     // interior t
    dis_b[tid] = rsqrtf(rs + 1.f);     // t in {0,127}
  }
  __syncthreads();

  // ---- sigma: two endpoint passes on thread halves, barrier-parallel ----
  const int pass = tid >> 7, idx = tid & 127;
  const int pb = pass * 256;
  const float mu = pass ? -MU_MIN : MU_MIN;
  for (int e = idx; e < 256; e += 128) {
    const int f = e >> 4, g = e & 15;
    float gv = -dis_i[f] * Bsh[e] * dis_i[g];
    if (f == g) gv += 1.f - mu * dis_i[f] * dis_i[f];
    Pb[pb + e] = gv;
  }
  __syncthreads();
  for (int e = idx; e < 256; e += 128) {       // H0 = G^T G (symmetric PSD)
    const int r = e >> 4, q = e & 15;
    float s = 0.f;
    #pragma unroll
    for (int k = 0; k < 16; k++) s += Pb[pb + k * 16 + r] * Pb[pb + k * 16 + q];
    H0[pb + e] = s;
    Qb[pb + e] = s;
  }
  __syncthreads();
  float* cur = Qb;
  float* nxt = Pb;
  #pragma unroll 1
  for (int it = 0; it < 8; it++) {             // cur -> cur^2/tr^2 (H^256 total)
    if (idx == 0) {
      float tr = 0.f;
      #pragma unroll
      for (int d = 0; d < 16; d++) tr += cur[pb + d * 17];
      scl[pass] = 1.f / (tr * tr);
    }
    __syncthreads();
    const float s2 = scl[pass];
    for (int e = idx; e < 256; e += 128) {
      const int r = e >> 4, q = e & 15;
      const float4* rr = (const float4*)(cur + pb + r * 16);  // symmetric: col = row
      const float4* qq = (const float4*)(cur + pb + q * 16);
      float s = 0.f;
      #pragma unroll
      for (int k4 = 0; k4 < 4; k4++) {
        const float4 a = rr[k4], b = qq[k4];
        s += a.x * b.x + a.y * b.y + a.z * b.z + a.w * b.w;
      }
      nxt[pb + e] = s * s2;
    }
    __syncthreads();
    float* tmp = cur; cur = nxt; nxt = tmp;
  }
  if (idx == 0) {                              // dominant column = argmax diag of H^256
    int bj = 0; float bd = -1.f;
    #pragma unroll
    for (int d = 0; d < 16; d++) {
      const float v = cur[pb + d * 17];
      if (v > bd) { bd = v; bj = d; }
    }
    jst[pass] = bj;
  }
  __syncthreads();
  if (idx < 16) {                              // Rayleigh quotient vs H0
    const int r = idx, js = jst[pass];
    const float vr = cur[pb + r * 16 + js];
    float hv = 0.f;
    #pragma unroll
    for (int q = 0; q < 16; q++) hv += H0[pb + r * 16 + q] * cur[pb + q * 16 + js];
    const float num = dot16(vr * hv);
    const float den = dot16(vr * vr);
    if (r == 0) lamsh[pass] = num / fmaxf(den, 1e-30f);
  }
  __syncthreads();
  if (tid == 0) {
    const float lam = fmaxf(fmaxf(lamsh[0], lamsh[1]), 1e-20f);
    csh[0] = 2.f / sqrtf(lam);                 // c = 2 / sigma
  }
  __syncthreads();

  // ---- D blocks (only 2 distinct: interior, boundary) ----
  const float c = csh[0];
  const int r = tid >> 4, q = tid & 15;
  Dint[tid] = ((r == q) ? (c - 1.f) : 0.f) - c * dis_i[r] * dis_i[q] * Bsh[tid];
  Dbnd[tid] = ((r == q) ? (c - 1.f) : 0.f) - c * dis_b[r] * dis_b[q] * Bsh[tid];
  __syncthreads();
  {
    float s0 = 0.f, s1 = 0.f;
    #pragma unroll
    for (int k = 0; k < 16; k++) {
      s0 += Dint[r * 16 + k] * Dint[k * 16 + q];
      s1 += Dbnd[r * 16 + k] * Dbnd[k * 16 + q];
    }
    DDint[tid] = s0;
    DDbnd[tid] = s1;
  }
  __syncthreads();

  // ---- build M variants: one (fo,o) pair per thread ----
  int tvs[4], nv;
  if (tg == 0)      { nv = 4; tvs[0] = 8; tvs[1] = 0;   tvs[2] = 1;   tvs[3] = 2;   }
  else if (tg == 7) { nv = 4; tvs[0] = 8; tvs[1] = 125; tvs[2] = 126; tvs[3] = 127; }
  else              { nv = 1; tvs[0] = 8; }

  const int fo = r;   // input feature f
  const int o = q;    // output channel
  auto uat = [&](int a_, int ff) -> float {
    return (a_ == 0 || a_ == 127) ? dis_b[ff] : dis_i[ff];
  };

  #pragma unroll 1
  for (int v = 0; v < nv; v++) {
    const int t = tvs[v];
    const float* D0p = (t == 0 || t == 127) ? Dbnd : Dint;
    const float* Dmp = (t == 1)   ? Dbnd : Dint;   // t-1 boundary iff t==1 (t==0 guarded off)
    const float* Dpp = (t == 126) ? Dbnd : Dint;   // t+1 boundary iff t==126 (t==127 guarded off)
    const float* DDp = (t == 0 || t == 127) ? DDbnd : DDint;
    float m[5];
    const float ut_f = uat(t, fo);

    // dt = 0
    {
      float acc = Wsh[fo * 16 + o];
      const float diag0 = 2.f * c * c * ut_f * ut_f *
                          ((t > 0 ? uat(t - 1, fo) * uat(t - 1, fo) : 0.f) +
                           (t < 127 ? uat(t + 1, fo) * uat(t + 1, fo) : 0.f)) - 1.f;
      #pragma unroll
      for (int fp = 0; fp < 16; fp++) {
        acc += D0p[fo * 16 + fp] * Wsh[256 + fp * 16 + o];
        const float p2 = 2.f * DDp[fo * 16 + fp] + ((fo == fp) ? diag0 : 0.f);
        acc += p2 * Wsh[512 + fp * 16 + o];
      }
      m[2] = acc;
    }
    // dt = +1
    if (t < 127) {
      const float gf = -c * uat(t + 1, fo) * ut_f;
      float acc = gf * Wsh[256 + fo * 16 + o];
      #pragma unroll
      for (int fp = 0; fp < 16; fp++) {
        const float gq = -c * uat(t + 1, fp) * uat(t, fp);
        acc += 2.f * (gf * D0p[fo * 16 + fp] + Dpp[fo * 16 + fp] * gq) * Wsh[512 + fp * 16 + o];
      }
      m[3] = acc;
    } else m[3] = 0.f;
    // dt = -1
    if (t > 0) {
      const float gf = -c * uat(t - 1, fo) * ut_f;
      float acc = gf * Wsh[256 + fo * 16 + o];
      #pragma unroll
      for (int fp = 0; fp < 16; fp++) {
        const float gq = -c * uat(t - 1, fp) * uat(t, fp);
        acc += 2.f * (Dmp[fo * 16 + fp] * gq + gf * D0p[fo * 16 + fp]) * Wsh[512 + fp * 16 + o];
      }
      m[1] = acc;
    } else m[1] = 0.f;
    // dt = +/-2 (diagonal)
    m[4] = (t < 126) ? (2.f * c * c * uat(t + 2, fo) * uat(t + 1, fo) * uat(t + 1, fo) * ut_f
                        * Wsh[512 + fo * 16 + o]) : 0.f;
    m[0] = (t > 1) ? (2.f * c * c * uat(t - 2, fo) * uat(t - 1, fo) * uat(t - 1, fo) * ut_f
                      * Wsh[512 + fo * 16 + o]) : 0.f;

    float* Mv = Msh + v * MSTRIDE;
    #pragma unroll
    for (int d5 = 0; d5 < 5; d5++)
      Mv[d5 * 256 + fo * 16 + o] = m[d5];     // fo*16+o consecutive over wave: 2-way, free
  }

  // ---- flush prefetched x chunk 0 to LDS; one barrier covers Msh + xs ----
  {
    const int cb = tid / 80, rem = tid % 80;
    const int rrow = rem >> 2, qq = rem & 3;
    *(float4*)(xs + cb * 400 + rrow * 20 + qq * 4) = xpre0;
  }
  if (tid < 64) {
    const int idx2 = tid + 256;
    const int cb = idx2 / 80, rem = idx2 % 80;
    const int rrow = rem >> 2, qq = rem & 3;
    *(float4*)(xs + cb * 400 + rrow * 20 + qq * 4) = xpre1;
  }
  __syncthreads();

  // ---- per-thread M[80] column from the right variant ----
  const int tl = r;                    // thread covers t = t0 + tl, channel o
  const int t = t0 + tl;
  int vm = 0;
  if (tg == 0)      vm = (tl < 3)  ? tl + 1  : 0;
  else if (tg == 7) vm = (tl > 12) ? tl - 12 : 0;
  float M[80];
  {
    const float* Mv = Msh + vm * MSTRIDE;
    #pragma unroll
    for (int dt = 0; dt < 5; dt++)
      #pragma unroll
      for (int f = 0; f < 16; f++)
        M[dt * 16 + f] = Mv[dt * 256 + f * 16 + o];   // broadcast over tl (interior blocks)
  }
  const float bo = bias[o];

  // ---- conv: 4 chunks x 4 batches (chunk 0 pre-staged) ----
  for (int cc = 0; cc < 4; cc++) {
    if (cc > 0) {
      __syncthreads();
      for (int ix = tid; ix < 320; ix += 256) {
        const int cb = ix / 80, rem = ix % 80;
        const int rrow = rem >> 2, qq = rem & 3;
        int gr = t0 - 2 + rrow;
        gr = gr < 0 ? 0 : (gr > 127 ? 127 : gr);  // clamped rows hit M==0 entries
        const float4 vv = *(const float4*)(x + ((size_t)(b0 + cc * 4 + cb) * 128 + gr) * 16 + qq * 4);
        *(float4*)(xs + cb * 400 + rrow * 20 + qq * 4) = vv;
      }
      __syncthreads();
    }
    #pragma unroll
    for (int cb = 0; cb < 4; cb++) {
      float acc0 = bo, acc1 = 0.f;
      #pragma unroll
      for (int dt = 0; dt < 5; dt++) {
        const float* xr = xs + cb * 400 + (tl + dt) * 20;
        const float4 xa = *(const float4*)(xr);
        const float4 xb = *(const float4*)(xr + 4);
        const float4 xc = *(const float4*)(xr + 8);
        const float4 xd = *(const float4*)(xr + 12);
        const float* Mp = M + dt * 16;
        acc0 += xa.x * Mp[0] + xa.y * Mp[1] + xa.z * Mp[2] + xa.w * Mp[3]
              + xb.x * Mp[4] + xb.y * Mp[5] + xb.z * Mp[6] + xb.w * Mp[7];
        acc1 += xc.x * Mp[8] + xc.y * Mp[9] + xc.z * Mp[10] + xc.w * Mp[11]
              + xd.x * Mp[12] + xd.y * Mp[13] + xd.z * Mp[14] + xd.w * Mp[15];
      }
      out[((size_t)(b0 + cc * 4 + cb) * 128 + t) * 16 + o] = acc0 + acc1;
    }
  }
}

extern "C" void kernel_launch(void* const* d_in, const int* in_sizes, int n_in,
                              void* d_out, int out_size, void* d_ws, size_t ws_size,
                              hipStream_t stream) {
  const float* x    = (const float*)d_in[0];  // [1024,128,16]
  const float* W    = (const float*)d_in[1];  // [3,16,16]
  const float* bias = (const float*)d_in[2];  // [16]
  const float* adj  = (const float*)d_in[3];  // [16,16]
  float* out = (float*)d_out;
  (void)d_ws; (void)ws_size;                  // workspace unused

  k_all<<<dim3(64, 8), dim3(256), 0, stream>>>(adj, W, x, bias, out);
}

// Round 9
// 86.082 us; speedup vs baseline: 1.0097x; 1.0097x over previous
//
#include <hip/hip_runtime.h>
#include <math.h>

// SGConv, single fused kernel. out[b,t,o] = bias[o] + sum_{dt,f} x[b,t+dt,f]*M[t][dt][f][o].
// sigma = ||lap||_2 reduced via tensor structure to max over endpoint mu=-+2cos(pi/129)
// of lam_max(G_mu^T G_mu) (16x16): 8 trace-normalized squarings (H^256) + Rayleigh.
// R8->R9: barrier diet. sigma squaring loop now 1 barrier/iter (per-thread redundant
// trace broadcast instead of scl[] round-trip), H0 built on-the-fly from B,u (G never
// materialized). Conv double-buffered: chunk c+1 prefetched into registers right after
// the barrier (HBM latency overlaps chunk-c FMAs), written to the alternate LDS buffer
// -> 1 barrier/chunk instead of 2.
// M-structure: only 7 distinct t-patterns (D_0==D_127); <=4 variants per block, one
// (fo,o) pair per thread (R5 lesson: never per-thread-all-fo / stride-256-across-tl).

#define MU_MIN (-1.99940694f)   // -2*cos(pi/129)
#define MSTRIDE 1300            // variant stride: 1300 mod 32 = 20 -> conflict-free-ish

__device__ __forceinline__ float dot16(float x) {  // sum over a 16-lane group
  x += __shfl_xor(x, 1);
  x += __shfl_xor(x, 2);
  x += __shfl_xor(x, 4);
  x += __shfl_xor(x, 8);
  return x;
}

__global__ __launch_bounds__(256) void k_all(const float* __restrict__ adj,
                                             const float* __restrict__ W,
                                             const float* __restrict__ x,
                                             const float* __restrict__ bias,
                                             float* __restrict__ out) {
  const int bg = blockIdx.x;           // 0..63 -> 16 batches each
  const int tg = blockIdx.y;           // 0..7  -> 16 t each
  const int t0 = tg * 16, b0 = bg * 16;
  const int tid = threadIdx.x;

  __shared__ float Bsh[256], Wsh[768];
  __shared__ float dis_i[16], dis_b[16], csh[1];
  __shared__ float H0[512], Pb[512], Qb[512];
  __shared__ float lamsh[2];
  __shared__ int jst[2];
  __shared__ float Dint[256], Dbnd[256], DDint[256], DDbnd[256];
  __shared__ float Msh[4 * MSTRIDE];
  __shared__ float xs[3200];           // double-buffered: 2 x (4 batches x 20 x 20)

  // ---- prefetch x chunk 0 into registers (flushed to xs[0] after M-build) ----
  float4 xpre0, xpre1;
  {
    const int cb = tid / 80, rem = tid % 80;
    const int rrow = rem >> 2, qq = rem & 3;
    int gr = t0 - 2 + rrow;
    gr = gr < 0 ? 0 : (gr > 127 ? 127 : gr);
    xpre0 = *(const float4*)(x + ((size_t)(b0 + cb) * 128 + gr) * 16 + qq * 4);
  }
  if (tid < 64) {
    const int ix = tid + 256;
    const int cb = ix / 80, rem = ix % 80;
    const int rrow = rem >> 2, qq = rem & 3;
    int gr = t0 - 2 + rrow;
    gr = gr < 0 ? 0 : (gr > 127 ? 127 : gr);
    xpre1 = *(const float4*)(x + ((size_t)(b0 + cb) * 128 + gr) * 16 + qq * 4);
  }

  // ---- B, W, degrees ----
  {
    const int f = tid >> 4, g = tid & 15;
    const float a = adj[tid];
    const float s = 1.f / (1.f + expf(-a));
    Bsh[tid] = (f == g) ? 1.f : s;     // B = feat + self-loop (asymmetric)
    Wsh[tid] = W[tid];
    Wsh[tid + 256] = W[tid + 256];
    Wsh[tid + 512] = W[tid + 512];
  }
  __syncthreads();
  if (tid < 16) {
    float rs = 0.f;
    #pragma unroll
    for (int j = 0; j < 16; j++) rs += Bsh[tid * 16 + j];  // row sums (d = sum axis=1)
    dis_i[tid] = rsqrtf(rs + 2.f);     // interior t
    dis_b[tid] = rsqrtf(rs + 1.f);     // t in {0,127}
  }
  __syncthreads();

  // ---- sigma: two endpoint passes on thread halves ----
  const int pass = tid >> 7, idx = tid & 127;
  const int pb = pass * 256;
  const float mu = pass ? -MU_MIN : MU_MIN;
  // H0 = G^T G built on the fly (G[k,j] = delta(1 - mu u_k^2) - u_k B[k,j] u_j)
  for (int e = idx; e < 256; e += 128) {
    const int r = e >> 4, q = e & 15;
    const float ur = dis_i[r], uq = dis_i[q];
    float s = 0.f;
    #pragma unroll
    for (int k = 0; k < 16; k++) {
      const float uk = dis_i[k];
      float gkr = -uk * Bsh[k * 16 + r] * ur;
      if (k == r) gkr += 1.f - mu * uk * uk;
      float gkq = -uk * Bsh[k * 16 + q] * uq;
      if (k == q) gkq += 1.f - mu * uk * uk;
      s += gkr * gkq;
    }
    H0[pb + e] = s;
    Qb[pb + e] = s;
  }
  __syncthreads();

  float* cur = Qb;
  float* nxt = Pb;
  #pragma unroll 1
  for (int it = 0; it < 8; it++) {     // cur -> cur^2/tr^2 (H^256 total); 1 barrier/iter
    float tr = 0.f;                    // redundant per-thread trace (broadcast reads)
    #pragma unroll
    for (int d = 0; d < 16; d++) tr += cur[pb + d * 17];
    const float s2 = 1.f / (tr * tr);
    for (int e = idx; e < 256; e += 128) {
      const int r = e >> 4, q = e & 15;
      const float4* rr = (const float4*)(cur + pb + r * 16);  // symmetric: col = row
      const float4* qq = (const float4*)(cur + pb + q * 16);
      float s = 0.f;
      #pragma unroll
      for (int k4 = 0; k4 < 4; k4++) {
        const float4 a = rr[k4], b = qq[k4];
        s += a.x * b.x + a.y * b.y + a.z * b.z + a.w * b.w;
      }
      nxt[pb + e] = s * s2;
    }
    __syncthreads();
    float* tmp = cur; cur = nxt; nxt = tmp;
  }
  if (idx == 0) {                      // dominant column = argmax diag of H^256
    int bj = 0; float bd = -1.f;
    #pragma unroll
    for (int d = 0; d < 16; d++) {
      const float v = cur[pb + d * 17];
      if (v > bd) { bd = v; bj = d; }
    }
    jst[pass] = bj;
  }
  __syncthreads();
  if (idx < 16) {                      // Rayleigh quotient vs H0
    const int r = idx, js = jst[pass];
    const float vr = cur[pb + r * 16 + js];
    float hv = 0.f;
    #pragma unroll
    for (int q = 0; q < 16; q++) hv += H0[pb + r * 16 + q] * cur[pb + q * 16 + js];
    const float num = dot16(vr * hv);
    const float den = dot16(vr * vr);
    if (r == 0) lamsh[pass] = num / fmaxf(den, 1e-30f);
  }
  __syncthreads();
  if (tid == 0) {
    const float lam = fmaxf(fmaxf(lamsh[0], lamsh[1]), 1e-20f);
    csh[0] = 2.f / sqrtf(lam);         // c = 2 / sigma
  }
  __syncthreads();

  // ---- D blocks (only 2 distinct: interior, boundary) ----
  const float c = csh[0];
  const int r = tid >> 4, q = tid & 15;
  Dint[tid] = ((r == q) ? (c - 1.f) : 0.f) - c * dis_i[r] * dis_i[q] * Bsh[tid];
  Dbnd[tid] = ((r == q) ? (c - 1.f) : 0.f) - c * dis_b[r] * dis_b[q] * Bsh[tid];
  __syncthreads();
  {
    float s0 = 0.f, s1 = 0.f;
    #pragma unroll
    for (int k = 0; k < 16; k++) {
      s0 += Dint[r * 16 + k] * Dint[k * 16 + q];
      s1 += Dbnd[r * 16 + k] * Dbnd[k * 16 + q];
    }
    DDint[tid] = s0;
    DDbnd[tid] = s1;
  }
  __syncthreads();

  // ---- build M variants: one (fo,o) pair per thread ----
  int tvs[4], nv;
  if (tg == 0)      { nv = 4; tvs[0] = 8; tvs[1] = 0;   tvs[2] = 1;   tvs[3] = 2;   }
  else if (tg == 7) { nv = 4; tvs[0] = 8; tvs[1] = 125; tvs[2] = 126; tvs[3] = 127; }
  else              { nv = 1; tvs[0] = 8; }

  const int fo = r;   // input feature f
  const int o = q;    // output channel
  auto uat = [&](int a_, int ff) -> float {
    return (a_ == 0 || a_ == 127) ? dis_b[ff] : dis_i[ff];
  };

  #pragma unroll 1
  for (int v = 0; v < nv; v++) {
    const int t = tvs[v];
    const float* D0p = (t == 0 || t == 127) ? Dbnd : Dint;
    const float* Dmp = (t == 1)   ? Dbnd : Dint;   // t-1 boundary iff t==1
    const float* Dpp = (t == 126) ? Dbnd : Dint;   // t+1 boundary iff t==126
    const float* DDp = (t == 0 || t == 127) ? DDbnd : DDint;
    float m[5];
    const float ut_f = uat(t, fo);

    // dt = 0
    {
      float acc = Wsh[fo * 16 + o];
      const float diag0 = 2.f * c * c * ut_f * ut_f *
                          ((t > 0 ? uat(t - 1, fo) * uat(t - 1, fo) : 0.f) +
                           (t < 127 ? uat(t + 1, fo) * uat(t + 1, fo) : 0.f)) - 1.f;
      #pragma unroll
      for (int fp = 0; fp < 16; fp++) {
        acc += D0p[fo * 16 + fp] * Wsh[256 + fp * 16 + o];
        const float p2 = 2.f * DDp[fo * 16 + fp] + ((fo == fp) ? diag0 : 0.f);
        acc += p2 * Wsh[512 + fp * 16 + o];
      }
      m[2] = acc;
    }
    // dt = +1
    if (t < 127) {
      const float gf = -c * uat(t + 1, fo) * ut_f;
      float acc = gf * Wsh[256 + fo * 16 + o];
      #pragma unroll
      for (int fp = 0; fp < 16; fp++) {
        const float gq = -c * uat(t + 1, fp) * uat(t, fp);
        acc += 2.f * (gf * D0p[fo * 16 + fp] + Dpp[fo * 16 + fp] * gq) * Wsh[512 + fp * 16 + o];
      }
      m[3] = acc;
    } else m[3] = 0.f;
    // dt = -1
    if (t > 0) {
      const float gf = -c * uat(t - 1, fo) * ut_f;
      float acc = gf * Wsh[256 + fo * 16 + o];
      #pragma unroll
      for (int fp = 0; fp < 16; fp++) {
        const float gq = -c * uat(t - 1, fp) * uat(t, fp);
        acc += 2.f * (Dmp[fo * 16 + fp] * gq + gf * D0p[fo * 16 + fp]) * Wsh[512 + fp * 16 + o];
      }
      m[1] = acc;
    } else m[1] = 0.f;
    // dt = +/-2 (diagonal)
    m[4] = (t < 126) ? (2.f * c * c * uat(t + 2, fo) * uat(t + 1, fo) * uat(t + 1, fo) * ut_f
                        * Wsh[512 + fo * 16 + o]) : 0.f;
    m[0] = (t > 1) ? (2.f * c * c * uat(t - 2, fo) * uat(t - 1, fo) * uat(t - 1, fo) * ut_f
                      * Wsh[512 + fo * 16 + o]) : 0.f;

    float* Mv = Msh + v * MSTRIDE;
    #pragma unroll
    for (int d5 = 0; d5 < 5; d5++)
      Mv[d5 * 256 + fo * 16 + o] = m[d5];     // consecutive over wave: 2-way, free
  }

  // ---- flush prefetched x chunk 0 to xs[0]; one barrier covers Msh + xs ----
  {
    const int cb = tid / 80, rem = tid % 80;
    const int rrow = rem >> 2, qq = rem & 3;
    *(float4*)(xs + cb * 400 + rrow * 20 + qq * 4) = xpre0;
  }
  if (tid < 64) {
    const int ix = tid + 256;
    const int cb = ix / 80, rem = ix % 80;
    const int rrow = rem >> 2, qq = rem & 3;
    *(float4*)(xs + cb * 400 + rrow * 20 + qq * 4) = xpre1;
  }
  __syncthreads();

  // ---- per-thread M[80] column from the right variant ----
  const int tl = r;                    // thread covers t = t0 + tl, channel o
  const int t = t0 + tl;
  int vm = 0;
  if (tg == 0)      vm = (tl < 3)  ? tl + 1  : 0;
  else if (tg == 7) vm = (tl > 12) ? tl - 12 : 0;
  float M[80];
  {
    const float* Mv = Msh + vm * MSTRIDE;
    #pragma unroll
    for (int dt = 0; dt < 5; dt++)
      #pragma unroll
      for (int f = 0; f < 16; f++)
        M[dt * 16 + f] = Mv[dt * 256 + f * 16 + o];   // broadcast over tl (interior)
  }
  const float bo = bias[o];

  // ---- conv: 4 chunks x 4 batches, double-buffered with register prefetch ----
  for (int cc = 0; cc < 4; cc++) {
    const float* xbuf = xs + (cc & 1) * 1600;
    float4 pre0, pre1;
    if (cc < 3) {                      // issue next chunk's loads NOW (overlap FMAs)
      const int cb = tid / 80, rem = tid % 80;
      const int rrow = rem >> 2, qq = rem & 3;
      int gr = t0 - 2 + rrow;
      gr = gr < 0 ? 0 : (gr > 127 ? 127 : gr);
      pre0 = *(const float4*)(x + ((size_t)(b0 + (cc + 1) * 4 + cb) * 128 + gr) * 16 + qq * 4);
      if (tid < 64) {
        const int ix = tid + 256;
        const int cb2 = ix / 80, rem2 = ix % 80;
        const int rrow2 = rem2 >> 2, qq2 = rem2 & 3;
        int gr2 = t0 - 2 + rrow2;
        gr2 = gr2 < 0 ? 0 : (gr2 > 127 ? 127 : gr2);
        pre1 = *(const float4*)(x + ((size_t)(b0 + (cc + 1) * 4 + cb2) * 128 + gr2) * 16 + qq2 * 4);
      }
    }
    #pragma unroll
    for (int cb = 0; cb < 4; cb++) {
      float acc0 = bo, acc1 = 0.f;
      #pragma unroll
      for (int dt = 0; dt < 5; dt++) {
        const float* xr = xbuf + cb * 400 + (tl + dt) * 20;
        const float4 xa = *(const float4*)(xr);
        const float4 xb = *(const float4*)(xr + 4);
        const float4 xc = *(const float4*)(xr + 8);
        const float4 xd = *(const float4*)(xr + 12);
        const float* Mp = M + dt * 16;
        acc0 += xa.x * Mp[0] + xa.y * Mp[1] + xa.z * Mp[2] + xa.w * Mp[3]
              + xb.x * Mp[4] + xb.y * Mp[5] + xb.z * Mp[6] + xb.w * Mp[7];
        acc1 += xc.x * Mp[8] + xc.y * Mp[9] + xc.z * Mp[10] + xc.w * Mp[11]
              + xd.x * Mp[12] + xd.y * Mp[13] + xd.z * Mp[14] + xd.w * Mp[15];
      }
      out[((size_t)(b0 + cc * 4 + cb) * 128 + t) * 16 + o] = acc0 + acc1;
    }
    if (cc < 3) {                      // write next chunk to the OTHER buffer
      float* nbuf = xs + ((cc + 1) & 1) * 1600;
      {
        const int cb = tid / 80, rem = tid % 80;
        const int rrow = rem >> 2, qq = rem & 3;
        *(float4*)(nbuf + cb * 400 + rrow * 20 + qq * 4) = pre0;
      }
      if (tid < 64) {
        const int ix = tid + 256;
        const int cb = ix / 80, rem = ix % 80;
        const int rrow = rem >> 2, qq = rem & 3;
        *(float4*)(nbuf + cb * 400 + rrow * 20 + qq * 4) = pre1;
      }
      __syncthreads();
    }
  }
}

extern "C" void kernel_launch(void* const* d_in, const int* in_sizes, int n_in,
                              void* d_out, int out_size, void* d_ws, size_t ws_size,
                              hipStream_t stream) {
  const float* x    = (const float*)d_in[0];  // [1024,128,16]
  const float* W    = (const float*)d_in[1];  // [3,16,16]
  const float* bias = (const float*)d_in[2];  // [16]
  const float* adj  = (const float*)d_in[3];  // [16,16]
  float* out = (float*)d_out;
  (void)d_ws; (void)ws_size;                  // workspace unused

  k_all<<<dim3(64, 8), dim3(256), 0, stream>>>(adj, W, x, bias, out);
}